// Round 11
// baseline (83.407 us; speedup 1.0000x reference)
//
#include <hip/hip_runtime.h>

#define NPTS   800000
#define NPB    200000
#define NSEG   131072
#define OUT_OFF (NSEG*4)   // float offset of second output
#define BN_EPS 1e-5f
#define BCAP   2048        // per-bucket capacity (mean fill ~1562, +12 sigma)
#define PLANE  (512*BCAP)  // u32 per payload plane

typedef __attribute__((ext_vector_type(8))) __bf16 bf16x8;
typedef __attribute__((ext_vector_type(4))) float  f32x4;

#define MFMA16 __builtin_amdgcn_mfma_f32_16x16x32_bf16

// ---------- helpers ----------
__device__ __forceinline__ unsigned short f2bf(float f) {  // RTNE float->bf16 bits
    unsigned u = __float_as_uint(f);
    u += 0x7fffu + ((u >> 16) & 1u);
    return (unsigned short)(u >> 16);
}
__device__ __forceinline__ unsigned enc16(unsigned short b) {  // order-preserving bf16->u16 (>0 always)
    return (b & 0x8000u) ? ((~(unsigned)b) & 0xFFFFu) : ((unsigned)b | 0x8000u);
}
__device__ __forceinline__ unsigned dec16(unsigned e) {        // inverse
    return (e >= 0x8000u) ? (e & 0x7FFFu) : ((~e) & 0xFFFFu);
}

// ---------- k_fold: fold BN into weights, collapse w4@wc, bf16 [N][K]; zero bucketFill ----------
__global__ void k_fold(const float* __restrict__ g0, const float* __restrict__ be0,
                       const float* __restrict__ m0, const float* __restrict__ v0,
                       const float* __restrict__ g1, const float* __restrict__ be1,
                       const float* __restrict__ m1, const float* __restrict__ v1,
                       const float* __restrict__ g2, const float* __restrict__ be2,
                       const float* __restrict__ m2, const float* __restrict__ v2,
                       const float* __restrict__ g3, const float* __restrict__ be3,
                       const float* __restrict__ m3, const float* __restrict__ v3,
                       const float* __restrict__ w1, const float* __restrict__ b1,
                       const float* __restrict__ w2, const float* __restrict__ b2,
                       const float* __restrict__ w3, const float* __restrict__ b3,
                       const float* __restrict__ w4, const float* __restrict__ b4,
                       const float* __restrict__ wc, const float* __restrict__ bc,
                       unsigned short* __restrict__ WT1, float* __restrict__ c1,
                       unsigned short* __restrict__ WT2, float* __restrict__ c2,
                       unsigned short* __restrict__ WT3, float* __restrict__ c3,
                       unsigned short* __restrict__ WT4, float* __restrict__ c4,
                       unsigned* __restrict__ bucketFill) {
    __shared__ float swc[4096];   // wc staged for the WT4 blocks (160..175)
    int id = blockIdx.x * 256 + threadIdx.x;
    // WT4 branch is block-uniform (boundaries 40960=160*256, 45056=176*256)
    if (blockIdx.x >= 160 && blockIdx.x < 176) {
        for (int i = threadIdx.x; i < 4096; i += 256) swc[i] = wc[i];
        __syncthreads();
        int t = id - 40960; int j = t >> 8, k = t & 255;   // j constant per block, k = tid
        float acc = 0.f;
        const float4* w4r = reinterpret_cast<const float4*>(w4 + k*256);
        #pragma unroll 4
        for (int i4 = 0; i4 < 64; ++i4) {
            float4 w = w4r[i4];
            acc += w.x * swc[(i4*4+0)*16 + j] + w.y * swc[(i4*4+1)*16 + j]
                 + w.z * swc[(i4*4+2)*16 + j] + w.w * swc[(i4*4+3)*16 + j];
        }
        WT4[t] = f2bf(acc);
        return;
    }
    if (id < 32768) {                          // WT3[j][k] = w3[k][j]*s3[j]
        int j = id >> 7, k = id & 127;
        float s = g3[j] * rsqrtf(v3[j] + BN_EPS);
        WT3[id] = f2bf(w3[k*256 + j] * s);
    } else if (id < 40960) {                   // WT2[j][k] = w2[k][j]*s2[j]
        int t = id - 32768; int j = t >> 6, k = t & 63;
        float s = g2[j] * rsqrtf(v2[j] + BN_EPS);
        WT2[t] = f2bf(w2[k*128 + j] * s);
    } else if (id < 47104) {                   // WT1[j][k] = s0[k]*w1[k][j]*s1[j], K padded to 32
        int t = id - 45056; int j = t >> 5, k = t & 31;
        float val = 0.f;
        if (k < 9) {
            float s0 = g0[k] * rsqrtf(v0[k] + BN_EPS);
            float s1 = g1[j] * rsqrtf(v1[j] + BN_EPS);
            val = s0 * w1[k*64 + j] * s1;
        }
        WT1[t] = f2bf(val);
    } else if (id < 47168) {                   // c1
        int j = id - 47104;
        float s1 = g1[j] * rsqrtf(v1[j] + BN_EPS);
        float acc = b1[j];
        for (int k = 0; k < 9; ++k) {
            float s0 = g0[k] * rsqrtf(v0[k] + BN_EPS);
            float t0 = be0[k] - m0[k] * s0;
            acc += t0 * w1[k*64 + j];
        }
        c1[j] = (acc - m1[j]) * s1 + be1[j];
    } else if (id < 47296) {                   // c2
        int j = id - 47168;
        float s = g2[j] * rsqrtf(v2[j] + BN_EPS);
        c2[j] = (b2[j] - m2[j]) * s + be2[j];
    } else if (id < 47552) {                   // c3
        int j = id - 47296;
        float s = g3[j] * rsqrtf(v3[j] + BN_EPS);
        c3[j] = (b3[j] - m3[j]) * s + be3[j];
    } else if (id < 47568) {                   // c4 = b4 @ wc + bc
        int j = id - 47552;
        float acc = bc[j];
        for (int i = 0; i < 256; ++i) acc += b4[i] * wc[i*16 + j];
        c4[j] = acc;
    } else if (id < 48080) {                   // zero 512 bucket fill counters
        bucketFill[id - 47568] = 0u;
    }
}

// ---------- kC: feature-carry bucketing. 1600 pts/block (one batch), 128 local slots ----------
// payload (SoA, 5 planes): w0 = (v<<16)|e0 ; w1 = e1|(e2<<16) ; ... ; w4 = e7|(e8<<16)
__global__ void __launch_bounds__(512)
kC(const int* __restrict__ ind, const float* __restrict__ fea,
   unsigned* __restrict__ bucketFill, unsigned* __restrict__ bP) {
    __shared__ unsigned lh[128], gb[128];
    __shared__ unsigned stash[5][128*24];   // 60 KB
    const int t = threadIdx.x;
    const int base = blockIdx.x * 1600;     // 800000 = 500*1600; block fully within one batch
    const int b0 = base / NPB;
    if (t < 128) lh[t] = 0u;
    __syncthreads();
    int loc[4]; unsigned slot[4]; unsigned pw[4][5];
    #pragma unroll
    for (int i = 0; i < 4; ++i) {
        int pl = i*512 + t;
        if (pl < 1600) {
            int p = base + pl;
            int ix = ind[p*3], iy = ind[p*3+1], iz = ind[p*3+2];
            loc[i] = ix*4 + (iy >> 3);
            unsigned v = (unsigned)((iy & 7)*32 + iz);
            const float* fp = fea + (size_t)p*9;
            float4 q0 = *reinterpret_cast<const float4*>(fp);
            float4 q1 = *reinterpret_cast<const float4*>(fp + 4);
            float  f8 = fp[8];
            unsigned e0 = enc16(f2bf(q0.x)), e1 = enc16(f2bf(q0.y));
            unsigned e2 = enc16(f2bf(q0.z)), e3 = enc16(f2bf(q0.w));
            unsigned e4 = enc16(f2bf(q1.x)), e5 = enc16(f2bf(q1.y));
            unsigned e6 = enc16(f2bf(q1.z)), e7 = enc16(f2bf(q1.w));
            unsigned e8 = enc16(f2bf(f8));
            pw[i][0] = (v << 16) | e0;
            pw[i][1] = e1 | (e2 << 16);
            pw[i][2] = e3 | (e4 << 16);
            pw[i][3] = e5 | (e6 << 16);
            pw[i][4] = e7 | (e8 << 16);
            slot[i] = atomicAdd(&lh[loc[i]], 1u);
            if (slot[i] < 24u) {
                #pragma unroll
                for (int w = 0; w < 5; ++w) stash[w][loc[i]*24 + slot[i]] = pw[i][w];
            }
        } else loc[i] = -1;
    }
    __syncthreads();
    if (t < 128 && lh[t] > 0u) gb[t] = atomicAdd(&bucketFill[b0*128 + t], lh[t]);
    __syncthreads();
    // coalesced-run flush
    for (int idx = t; idx < 128*24; idx += 512) {
        int s = idx / 24, e = idx - s*24;
        unsigned n = lh[s]; if (n > 24u) n = 24u;
        if ((unsigned)e < n) {
            unsigned pos = gb[s] + (unsigned)e;
            if (pos < BCAP) {
                size_t off = (size_t)(b0*128 + s)*BCAP + pos;
                #pragma unroll
                for (int w = 0; w < 5; ++w) bP[(size_t)w*PLANE + off] = stash[w][idx];
            }
        }
    }
    // rare overflow
    #pragma unroll
    for (int i = 0; i < 4; ++i) if (loc[i] >= 0 && slot[i] >= 24u) {
        unsigned pos = gb[loc[i]] + slot[i];
        if (pos < BCAP) {
            size_t off = (size_t)(b0*128 + loc[i])*BCAP + pos;
            #pragma unroll
            for (int w = 0; w < 5; ++w) bP[(size_t)w*PLANE + off] = pw[i][w];
        }
    }
}

// ---------- kD: streaming per-bucket LDS atomicMax -> packed bf16 pooled + occ bits ----------
__global__ void __launch_bounds__(1024)
kD(const unsigned* __restrict__ bucketFill, const unsigned* __restrict__ bP,
   unsigned* __restrict__ pooledB, unsigned long long* __restrict__ occW) {
    __shared__ unsigned enc[256*9];
    const int t = threadIdx.x, bkt = blockIdx.x;
    for (int i = t; i < 2304; i += 1024) enc[i] = 0u;
    __syncthreads();
    unsigned n = bucketFill[bkt]; if (n > BCAP) n = BCAP;
    for (unsigned j = t; j < n; j += 1024) {
        size_t off = (size_t)bkt*BCAP + j;
        unsigned w0 = bP[off];
        unsigned w1 = bP[PLANE + off];
        unsigned w2 = bP[2*(size_t)PLANE + off];
        unsigned w3 = bP[3*(size_t)PLANE + off];
        unsigned w4 = bP[4*(size_t)PLANE + off];
        unsigned* eb = enc + (w0 >> 16)*9;
        atomicMax(eb+0, w0 & 0xFFFFu);
        atomicMax(eb+1, w1 & 0xFFFFu); atomicMax(eb+2, w1 >> 16);
        atomicMax(eb+3, w2 & 0xFFFFu); atomicMax(eb+4, w2 >> 16);
        atomicMax(eb+5, w3 & 0xFFFFu); atomicMax(eb+6, w3 >> 16);
        atomicMax(eb+7, w4 & 0xFFFFu); atomicMax(eb+8, w4 >> 16);
    }
    __syncthreads();
    if (t < 256) {
        int occ = (enc[t*9] != 0u) ? 1 : 0;
        unsigned long long m = __ballot(occ);
        if ((t & 63) == 0) occW[bkt*4 + (t >> 6)] = m;
    }
    // write packed bf16 pooled rows (zero for empty voxels)
    for (int e2 = t; e2 < 1152; e2 += 1024) {
        int ea = 2*e2, eb2 = ea + 1;
        int va = ea / 9, vb = eb2 / 9;
        unsigned da = enc[va*9] ? dec16(enc[ea])  : 0u;
        unsigned db = enc[vb*9] ? dec16(enc[eb2]) : 0u;
        pooledB[(size_t)bkt*1152 + e2] = da | (db << 16);
    }
}

// ---------- persistent MFMA MLP with per-block occupancy scan + fused compaction ----------
// A := weights WT[N][K]; B := activations. D: col(lane&15)=row r, rows = n = kg*4+reg.
// 512 blocks x 4 tiles; waves_per_eu(4,4) pins VGPR cap 128 -> 2 blocks/CU co-resident.

__device__ __forceinline__ void store4(char* base, int r, int strideElems, int n, f32x4 acc) {
    union { __bf16 h[4]; uint2 u; } pk;
    #pragma unroll
    for (int i = 0; i < 4; ++i) pk.h[i] = (__bf16)fmaxf(acc[i], 0.f);
    int s = n >> 3;
    *reinterpret_cast<uint2*>(base + r*strideElems*2 + ((s ^ (r & 7)) << 4) + (n & 4)*2) = pk.u;
}

__global__ void __launch_bounds__(512) __attribute__((amdgpu_waves_per_eu(4, 4)))
k_mlp(const unsigned* __restrict__ pooledB,
      const unsigned long long* __restrict__ occW,
      const unsigned short* __restrict__ WT1, const float* __restrict__ c1,
      const unsigned short* __restrict__ WT2, const float* __restrict__ c2,
      const unsigned short* __restrict__ WT3, const float* __restrict__ c3,
      const unsigned short* __restrict__ WT4, const float* __restrict__ c4,
      float* __restrict__ unqOut, float* __restrict__ outF) {
    __shared__ __align__(16) char lds[61440];
    char* Rin = lds;            // 4 KB,  stride 32 elems (K-pad zeroed once)
    char* H1  = lds + 4096;     // 8 KB,  stride 64
    char* H2  = lds + 12288;    // 16 KB, stride 128
    char* H3  = lds + 28672;    // 32 KB, stride 256 (scan scratch before first use)
    const int tid = threadIdx.x;
    const int wv = tid >> 6, lane = tid & 63;
    const int r16 = lane & 15, kg = lane >> 4;

    for (int i = tid; i < 1024; i += 512) reinterpret_cast<unsigned*>(Rin)[i] = 0u;

    // resident weights: L1, L2, L3 + biases (~60 VGPR); L4 prefetched per-tile
    const int ft1 = wv & 3;
    bf16x8 a1 = *reinterpret_cast<const bf16x8*>(WT1 + (ft1*16 + r16)*32 + kg*8);
    f32x4 c1v = *reinterpret_cast<const f32x4*>(c1 + ft1*16 + kg*4);
    bf16x8 a2[2];
    #pragma unroll
    for (int ks = 0; ks < 2; ++ks)
        a2[ks] = *reinterpret_cast<const bf16x8*>(WT2 + (wv*16 + r16)*64 + ks*32 + kg*8);
    f32x4 c2v = *reinterpret_cast<const f32x4*>(c2 + wv*16 + kg*4);
    bf16x8 a3[2][4]; f32x4 c3v[2];
    #pragma unroll
    for (int u = 0; u < 2; ++u) {
        int ft = wv*2 + u;
        #pragma unroll
        for (int ks = 0; ks < 4; ++ks)
            a3[u][ks] = *reinterpret_cast<const bf16x8*>(WT3 + (ft*16 + r16)*128 + ks*32 + kg*8);
        c3v[u] = *reinterpret_cast<const f32x4*>(c3 + ft*16 + kg*4);
    }

    // ---- prologue: per-block occupancy scan (scratch in H3 region) ----
    unsigned* sS  = reinterpret_cast<unsigned*>(H3);          // 512 u32
    unsigned* wbS = reinterpret_cast<unsigned*>(H3 + 2048);   // 4 u32
    unsigned pc0 = (unsigned)__popcll(occW[tid*4+0]);
    unsigned pc1 = (unsigned)__popcll(occW[tid*4+1]);
    unsigned pc2 = (unsigned)__popcll(occW[tid*4+2]);
    unsigned pc3 = (unsigned)__popcll(occW[tid*4+3]);
    unsigned psum = pc0 + pc1 + pc2 + pc3;
    sS[tid] = psum;
    __syncthreads();   // also orders Rin zero vs staging below
    for (int off = 1; off < 512; off <<= 1) {
        unsigned add = (tid >= off) ? sS[tid-off] : 0u;
        __syncthreads();
        sS[tid] += add;
        __syncthreads();
    }
    unsigned ex = sS[tid] - psum;      // exclusive prefix (per 4-word chunk)
    const unsigned tot = sS[511];
    #pragma unroll
    for (int k = 0; k < 4; ++k) {
        int tl = blockIdx.x + 512*k;
        if (tid == (tl >> 2)) {
            unsigned b = ex; int o = tl & 3;
            if (o > 0) b += pc0;
            if (o > 1) b += pc1;
            if (o > 2) b += pc2;
            wbS[k] = b;
        }
    }
    __syncthreads();
    unsigned wb[4];
    #pragma unroll
    for (int k = 0; k < 4; ++k) wb[k] = wbS[k];
    __syncthreads();   // wbS reads complete before H3 reused in L3

    int tile = blockIdx.x;
    unsigned pf;
    if (tid < 288) pf = pooledB[(size_t)tile*288 + tid];
    #pragma unroll 1
    for (int it = 0; it < 4; ++it) {
        // stage current tile input (packed bf16 -> swizzled LDS); K-pad cols stay zero
        if (tid < 288) {
            int ea = 2*tid, eb = ea + 1;
            int ra = ea / 9, ca = ea - ra*9;
            int rb = eb / 9, cb = eb - rb*9;
            *reinterpret_cast<unsigned short*>(Rin + ra*64 + (((ca>>3) ^ (ra&3))<<4) + (ca&7)*2)
                = (unsigned short)(pf & 0xFFFFu);
            *reinterpret_cast<unsigned short*>(Rin + rb*64 + (((cb>>3) ^ (rb&3))<<4) + (cb&7)*2)
                = (unsigned short)(pf >> 16);
        }
        unsigned long long w = occW[tile];
        unsigned base = wb[it];
        // prefetch next tile's input
        if (it < 3 && tid < 288) pf = pooledB[((size_t)tile + 512)*288 + tid];
        __syncthreads();                         // B1
        // L1: K=32 -> 64
        {
            const int rtb = (wv >> 2) * 2;
            #pragma unroll
            for (int i = 0; i < 2; ++i) {
                int r = (rtb + i)*16 + r16;
                bf16x8 b = *reinterpret_cast<const bf16x8*>(Rin + r*64 + ((kg ^ (r&3))<<4));
                f32x4 acc = MFMA16(a1, b, c1v, 0, 0, 0);
                store4(H1, r, 64, ft1*16 + kg*4, acc);
            }
        }
        __syncthreads();                         // B2
        // L2: K=64 -> 128
        #pragma unroll
        for (int rt = 0; rt < 4; ++rt) {
            int r = rt*16 + r16;
            bf16x8 b0 = *reinterpret_cast<const bf16x8*>(H1 + r*128 + ((kg ^ (r&7))<<4));
            bf16x8 b1 = *reinterpret_cast<const bf16x8*>(H1 + r*128 + (((4+kg) ^ (r&7))<<4));
            f32x4 acc = MFMA16(a2[0], b0, c2v, 0, 0, 0);
            acc = MFMA16(a2[1], b1, acc, 0, 0, 0);
            store4(H2, r, 128, wv*16 + kg*4, acc);
        }
        __syncthreads();                         // B3
        // L3: K=128 -> 256 (b-frags shared across the wave's two feature tiles)
        #pragma unroll
        for (int rt = 0; rt < 4; ++rt) {
            int r = rt*16 + r16;
            bf16x8 b[4];
            #pragma unroll
            for (int ks = 0; ks < 4; ++ks)
                b[ks] = *reinterpret_cast<const bf16x8*>(H2 + r*256 + (((ks*4+kg) ^ (r&7))<<4));
            #pragma unroll
            for (int u = 0; u < 2; ++u) {
                f32x4 acc = c3v[u];
                #pragma unroll
                for (int ks = 0; ks < 4; ++ks)
                    acc = MFMA16(a3[u][ks], b[ks], acc, 0, 0, 0);
                store4(H3, r, 256, (wv*2+u)*16 + kg*4, acc);
            }
        }
        // per-tile prefetch of L4 weights (waves 0-3); latency drains with B4
        bf16x8 a4[8]; f32x4 c4v;
        if (wv < 4) {
            #pragma unroll
            for (int ks = 0; ks < 8; ++ks)
                a4[ks] = *reinterpret_cast<const bf16x8*>(WT4 + r16*256 + ks*32 + kg*8);
            c4v = *reinterpret_cast<const f32x4*>(c4 + kg*4);
        }
        __syncthreads();                         // B4
        // L4 (waves 0-3) + unq (wave 4), both scattered by rank
        if (wv < 4) {
            int r = wv*16 + r16;
            f32x4 acc = c4v;
            #pragma unroll
            for (int ks = 0; ks < 8; ++ks) {
                bf16x8 b = *reinterpret_cast<const bf16x8*>(H3 + r*512 + (((ks*4+kg) ^ (r&7))<<4));
                acc = MFMA16(a4[ks], b, acc, 0, 0, 0);
            }
            unsigned rdense = base + (unsigned)__popcll(w & ((1ull << r) - 1ull));
            unsigned rk = ((w >> r) & 1ull) ? rdense
                        : tot + (unsigned)(tile*64 + r) - rdense;
            float4 o;
            o.x = fmaxf(acc[0], 0.f); o.y = fmaxf(acc[1], 0.f);
            o.z = fmaxf(acc[2], 0.f); o.w = fmaxf(acc[3], 0.f);
            *reinterpret_cast<float4*>(outF + (size_t)rk*16 + kg*4) = o;
        } else if (wv == 4) {
            int r = lane, k = tile*64 + r;
            unsigned rdense = base + (unsigned)__popcll(w & ((1ull << r) - 1ull));
            if ((w >> r) & 1ull) {
                reinterpret_cast<float4*>(unqOut)[rdense] =
                    make_float4((float)(k >> 15), (float)((k >> 10) & 31),
                                (float)((k >> 5) & 31), (float)(k & 31));
            } else {
                unsigned er = tot + (unsigned)k - rdense;
                reinterpret_cast<float4*>(unqOut)[er] = make_float4(-1.f,-1.f,-1.f,-1.f);
            }
        }
        tile += 512;
    }
}

extern "C" void kernel_launch(void* const* d_in, const int* in_sizes, int n_in,
                              void* d_out, int out_size, void* d_ws, size_t ws_size,
                              hipStream_t stream) {
    const float* pt_fea = (const float*)d_in[0];
    const int*   xy_ind = (const int*)  d_in[1];
    const float* g0 = (const float*)d_in[2],  *be0 = (const float*)d_in[3];
    const float* m0 = (const float*)d_in[4],  *v0  = (const float*)d_in[5];
    const float* g1 = (const float*)d_in[6],  *be1 = (const float*)d_in[7];
    const float* m1 = (const float*)d_in[8],  *v1  = (const float*)d_in[9];
    const float* g2 = (const float*)d_in[10], *be2 = (const float*)d_in[11];
    const float* m2 = (const float*)d_in[12], *v2  = (const float*)d_in[13];
    const float* g3 = (const float*)d_in[14], *be3 = (const float*)d_in[15];
    const float* m3 = (const float*)d_in[16], *v3  = (const float*)d_in[17];
    const float* w1 = (const float*)d_in[18], *b1  = (const float*)d_in[19];
    const float* w2 = (const float*)d_in[20], *b2  = (const float*)d_in[21];
    const float* w3 = (const float*)d_in[22], *b3  = (const float*)d_in[23];
    const float* w4 = (const float*)d_in[24], *b4  = (const float*)d_in[25];
    const float* wc = (const float*)d_in[26], *bc  = (const float*)d_in[27];

    float* dout = (float*)d_out;

    // workspace layout (u32 units)
    unsigned* ws0 = (unsigned*)d_ws;
    unsigned long long* occW = (unsigned long long*)ws0;     // 2048 u64 = [0,4096)
    unsigned* bucketFill = ws0 + 4096;                       // 512
    unsigned* pooledB    = ws0 + 4608;                       // 512*1152 packed bf16 pairs
    unsigned* bP         = pooledB + 512*1152;               // 5 planes x 512*BCAP
    unsigned* wtBase     = bP + 5*(size_t)PLANE;
    unsigned short* WT1  = (unsigned short*)wtBase;          // 64*32
    unsigned short* WT2  = WT1 + 2048;                       // 128*64
    unsigned short* WT3  = WT2 + 8192;                       // 256*128
    unsigned short* WT4  = WT3 + 32768;                      // 16*256
    float* c1 = (float*)(WT4 + 4096);
    float* c2 = c1 + 64;
    float* c3 = c2 + 128;
    float* c4 = c3 + 256;

    k_fold<<<188, 256, 0, stream>>>(g0,be0,m0,v0, g1,be1,m1,v1, g2,be2,m2,v2, g3,be3,m3,v3,
                                    w1,b1, w2,b2, w3,b3, w4,b4, wc,bc,
                                    WT1,c1, WT2,c2, WT3,c3, WT4,c4, bucketFill);
    kC<<<500, 512, 0, stream>>>(xy_ind, pt_fea, bucketFill, bP);
    kD<<<512, 1024, 0, stream>>>(bucketFill, bP, pooledB, occW);
    k_mlp<<<512, 512, 0, stream>>>(pooledB, occW,
                                   WT1,c1, WT2,c2, WT3,c3, WT4,c4, dout, dout + OUT_OFF);
}

// Round 12
// 60.388 us; speedup vs baseline: 1.3812x; 1.3812x over previous
//
#include <hip/hip_runtime.h>

#define NPTS   800000
#define NPB    200000
#define NSEG   131072
#define OUT_OFF (NSEG*4)   // float offset of second output
#define BN_EPS 1e-5f
#define BCAP   2048        // per-bucket capacity (mean fill ~1562, +12 sigma)
#define PLANE  (512*BCAP)  // u32 per payload plane

typedef __attribute__((ext_vector_type(8))) __bf16 bf16x8;
typedef __attribute__((ext_vector_type(4))) float  f32x4;

#define MFMA16 __builtin_amdgcn_mfma_f32_16x16x32_bf16

// ---------- helpers ----------
__device__ __forceinline__ unsigned short f2bf(float f) {  // RTNE float->bf16 bits
    unsigned u = __float_as_uint(f);
    u += 0x7fffu + ((u >> 16) & 1u);
    return (unsigned short)(u >> 16);
}
__device__ __forceinline__ unsigned enc16(unsigned short b) {  // order-preserving bf16->u16 (>0 always)
    return (b & 0x8000u) ? ((~(unsigned)b) & 0xFFFFu) : ((unsigned)b | 0x8000u);
}
__device__ __forceinline__ unsigned dec16(unsigned e) {        // inverse
    return (e >= 0x8000u) ? (e & 0x7FFFu) : ((~e) & 0xFFFFu);
}

// ---------- k_fold: fold BN into weights, collapse w4@wc, bf16 [N][K]; zero bucketFill ----------
__global__ void k_fold(const float* __restrict__ g0, const float* __restrict__ be0,
                       const float* __restrict__ m0, const float* __restrict__ v0,
                       const float* __restrict__ g1, const float* __restrict__ be1,
                       const float* __restrict__ m1, const float* __restrict__ v1,
                       const float* __restrict__ g2, const float* __restrict__ be2,
                       const float* __restrict__ m2, const float* __restrict__ v2,
                       const float* __restrict__ g3, const float* __restrict__ be3,
                       const float* __restrict__ m3, const float* __restrict__ v3,
                       const float* __restrict__ w1, const float* __restrict__ b1,
                       const float* __restrict__ w2, const float* __restrict__ b2,
                       const float* __restrict__ w3, const float* __restrict__ b3,
                       const float* __restrict__ w4, const float* __restrict__ b4,
                       const float* __restrict__ wc, const float* __restrict__ bc,
                       unsigned short* __restrict__ WT1, float* __restrict__ c1,
                       unsigned short* __restrict__ WT2, float* __restrict__ c2,
                       unsigned short* __restrict__ WT3, float* __restrict__ c3,
                       unsigned short* __restrict__ WT4, float* __restrict__ c4,
                       unsigned* __restrict__ bucketFill) {
    __shared__ float swc[4096];   // wc staged for the WT4 blocks (160..175)
    int id = blockIdx.x * 256 + threadIdx.x;
    // WT4 branch is block-uniform (boundaries 40960=160*256, 45056=176*256)
    if (blockIdx.x >= 160 && blockIdx.x < 176) {
        for (int i = threadIdx.x; i < 4096; i += 256) swc[i] = wc[i];
        __syncthreads();
        int t = id - 40960; int j = t >> 8, k = t & 255;   // j constant per block, k = tid
        float acc = 0.f;
        const float4* w4r = reinterpret_cast<const float4*>(w4 + k*256);
        #pragma unroll 4
        for (int i4 = 0; i4 < 64; ++i4) {
            float4 w = w4r[i4];
            acc += w.x * swc[(i4*4+0)*16 + j] + w.y * swc[(i4*4+1)*16 + j]
                 + w.z * swc[(i4*4+2)*16 + j] + w.w * swc[(i4*4+3)*16 + j];
        }
        WT4[t] = f2bf(acc);
        return;
    }
    if (id < 32768) {                          // WT3[j][k] = w3[k][j]*s3[j]
        int j = id >> 7, k = id & 127;
        float s = g3[j] * rsqrtf(v3[j] + BN_EPS);
        WT3[id] = f2bf(w3[k*256 + j] * s);
    } else if (id < 40960) {                   // WT2[j][k] = w2[k][j]*s2[j]
        int t = id - 32768; int j = t >> 6, k = t & 63;
        float s = g2[j] * rsqrtf(v2[j] + BN_EPS);
        WT2[t] = f2bf(w2[k*128 + j] * s);
    } else if (id < 47104) {                   // WT1[j][k] = s0[k]*w1[k][j]*s1[j], K padded to 32
        int t = id - 45056; int j = t >> 5, k = t & 31;
        float val = 0.f;
        if (k < 9) {
            float s0 = g0[k] * rsqrtf(v0[k] + BN_EPS);
            float s1 = g1[j] * rsqrtf(v1[j] + BN_EPS);
            val = s0 * w1[k*64 + j] * s1;
        }
        WT1[t] = f2bf(val);
    } else if (id < 47168) {                   // c1
        int j = id - 47104;
        float s1 = g1[j] * rsqrtf(v1[j] + BN_EPS);
        float acc = b1[j];
        for (int k = 0; k < 9; ++k) {
            float s0 = g0[k] * rsqrtf(v0[k] + BN_EPS);
            float t0 = be0[k] - m0[k] * s0;
            acc += t0 * w1[k*64 + j];
        }
        c1[j] = (acc - m1[j]) * s1 + be1[j];
    } else if (id < 47296) {                   // c2
        int j = id - 47168;
        float s = g2[j] * rsqrtf(v2[j] + BN_EPS);
        c2[j] = (b2[j] - m2[j]) * s + be2[j];
    } else if (id < 47552) {                   // c3
        int j = id - 47296;
        float s = g3[j] * rsqrtf(v3[j] + BN_EPS);
        c3[j] = (b3[j] - m3[j]) * s + be3[j];
    } else if (id < 47568) {                   // c4 = b4 @ wc + bc
        int j = id - 47552;
        float acc = bc[j];
        for (int i = 0; i < 256; ++i) acc += b4[i] * wc[i*16 + j];
        c4[j] = acc;
    } else if (id < 48080) {                   // zero 512 bucket fill counters
        bucketFill[id - 47568] = 0u;
    }
}

// ---------- kC: feature-carry bucketing. 1600 pts/block (one batch), 128 local slots ----------
// payload (SoA, 5 planes): w0 = (v<<16)|e0 ; w1 = e1|(e2<<16) ; ... ; w4 = e7|(e8<<16)
__global__ void __launch_bounds__(512)
kC(const int* __restrict__ ind, const float* __restrict__ fea,
   unsigned* __restrict__ bucketFill, unsigned* __restrict__ bP) {
    __shared__ unsigned lh[128], gb[128];
    __shared__ unsigned stash[5][128*24];   // 60 KB
    const int t = threadIdx.x;
    const int base = blockIdx.x * 1600;     // 800000 = 500*1600; block fully within one batch
    const int b0 = base / NPB;
    if (t < 128) lh[t] = 0u;
    __syncthreads();
    int loc[4]; unsigned slot[4]; unsigned pw[4][5];
    #pragma unroll
    for (int i = 0; i < 4; ++i) {
        int pl = i*512 + t;
        if (pl < 1600) {
            int p = base + pl;
            int ix = ind[p*3], iy = ind[p*3+1], iz = ind[p*3+2];
            loc[i] = ix*4 + (iy >> 3);
            unsigned v = (unsigned)((iy & 7)*32 + iz);
            const float* fp = fea + (size_t)p*9;
            float4 q0 = *reinterpret_cast<const float4*>(fp);
            float4 q1 = *reinterpret_cast<const float4*>(fp + 4);
            float  f8 = fp[8];
            unsigned e0 = enc16(f2bf(q0.x)), e1 = enc16(f2bf(q0.y));
            unsigned e2 = enc16(f2bf(q0.z)), e3 = enc16(f2bf(q0.w));
            unsigned e4 = enc16(f2bf(q1.x)), e5 = enc16(f2bf(q1.y));
            unsigned e6 = enc16(f2bf(q1.z)), e7 = enc16(f2bf(q1.w));
            unsigned e8 = enc16(f2bf(f8));
            pw[i][0] = (v << 16) | e0;
            pw[i][1] = e1 | (e2 << 16);
            pw[i][2] = e3 | (e4 << 16);
            pw[i][3] = e5 | (e6 << 16);
            pw[i][4] = e7 | (e8 << 16);
            slot[i] = atomicAdd(&lh[loc[i]], 1u);
            if (slot[i] < 24u) {
                #pragma unroll
                for (int w = 0; w < 5; ++w) stash[w][loc[i]*24 + slot[i]] = pw[i][w];
            }
        } else loc[i] = -1;
    }
    __syncthreads();
    if (t < 128 && lh[t] > 0u) gb[t] = atomicAdd(&bucketFill[b0*128 + t], lh[t]);
    __syncthreads();
    // coalesced-run flush
    for (int idx = t; idx < 128*24; idx += 512) {
        int s = idx / 24, e = idx - s*24;
        unsigned n = lh[s]; if (n > 24u) n = 24u;
        if ((unsigned)e < n) {
            unsigned pos = gb[s] + (unsigned)e;
            if (pos < BCAP) {
                size_t off = (size_t)(b0*128 + s)*BCAP + pos;
                #pragma unroll
                for (int w = 0; w < 5; ++w) bP[(size_t)w*PLANE + off] = stash[w][idx];
            }
        }
    }
    // rare overflow
    #pragma unroll
    for (int i = 0; i < 4; ++i) if (loc[i] >= 0 && slot[i] >= 24u) {
        unsigned pos = gb[loc[i]] + slot[i];
        if (pos < BCAP) {
            size_t off = (size_t)(b0*128 + loc[i])*BCAP + pos;
            #pragma unroll
            for (int w = 0; w < 5; ++w) bP[(size_t)w*PLANE + off] = pw[i][w];
        }
    }
}

// ---------- kD: streaming per-bucket LDS atomicMax -> packed bf16 pooled + occ bits ----------
__global__ void __launch_bounds__(1024)
kD(const unsigned* __restrict__ bucketFill, const unsigned* __restrict__ bP,
   unsigned* __restrict__ pooledB, unsigned long long* __restrict__ occW) {
    __shared__ unsigned enc[256*9];
    const int t = threadIdx.x, bkt = blockIdx.x;
    for (int i = t; i < 2304; i += 1024) enc[i] = 0u;
    __syncthreads();
    unsigned n = bucketFill[bkt]; if (n > BCAP) n = BCAP;
    for (unsigned j = t; j < n; j += 1024) {
        size_t off = (size_t)bkt*BCAP + j;
        unsigned w0 = bP[off];
        unsigned w1 = bP[PLANE + off];
        unsigned w2 = bP[2*(size_t)PLANE + off];
        unsigned w3 = bP[3*(size_t)PLANE + off];
        unsigned w4 = bP[4*(size_t)PLANE + off];
        unsigned* eb = enc + (w0 >> 16)*9;
        atomicMax(eb+0, w0 & 0xFFFFu);
        atomicMax(eb+1, w1 & 0xFFFFu); atomicMax(eb+2, w1 >> 16);
        atomicMax(eb+3, w2 & 0xFFFFu); atomicMax(eb+4, w2 >> 16);
        atomicMax(eb+5, w3 & 0xFFFFu); atomicMax(eb+6, w3 >> 16);
        atomicMax(eb+7, w4 & 0xFFFFu); atomicMax(eb+8, w4 >> 16);
    }
    __syncthreads();
    if (t < 256) {
        int occ = (enc[t*9] != 0u) ? 1 : 0;
        unsigned long long m = __ballot(occ);
        if ((t & 63) == 0) occW[bkt*4 + (t >> 6)] = m;
    }
    // write packed bf16 pooled rows (zero for empty voxels)
    for (int e2 = t; e2 < 1152; e2 += 1024) {
        int ea = 2*e2, eb2 = ea + 1;
        int va = ea / 9, vb = eb2 / 9;
        unsigned da = enc[va*9] ? dec16(enc[ea])  : 0u;
        unsigned db = enc[vb*9] ? dec16(enc[eb2]) : 0u;
        pooledB[(size_t)bkt*1152 + e2] = da | (db << 16);
    }
}

// ---------- persistent MFMA MLP with per-block occupancy scan + fused compaction ----------
// A := weights WT[N][K]; B := activations. D: col(lane&15)=row r, rows = n = kg*4+reg.
// 256 blocks x 8 tiles; 1 block/CU (register-file-limited; 2-block/CU attempts spill: R7/R11).

__device__ __forceinline__ void store4(char* base, int r, int strideElems, int n, f32x4 acc) {
    union { __bf16 h[4]; uint2 u; } pk;
    #pragma unroll
    for (int i = 0; i < 4; ++i) pk.h[i] = (__bf16)fmaxf(acc[i], 0.f);
    int s = n >> 3;
    *reinterpret_cast<uint2*>(base + r*strideElems*2 + ((s ^ (r & 7)) << 4) + (n & 4)*2) = pk.u;
}

__global__ void __launch_bounds__(512, 2)
k_mlp(const unsigned* __restrict__ pooledB,
      const unsigned long long* __restrict__ occW,
      const unsigned short* __restrict__ WT1, const float* __restrict__ c1,
      const unsigned short* __restrict__ WT2, const float* __restrict__ c2,
      const unsigned short* __restrict__ WT3, const float* __restrict__ c3,
      const unsigned short* __restrict__ WT4, const float* __restrict__ c4,
      float* __restrict__ unqOut, float* __restrict__ outF) {
    __shared__ __align__(16) char lds[61440];
    char* Rin = lds;            // 4 KB,  stride 32 elems (K-pad zeroed once)
    char* H1  = lds + 4096;     // 8 KB,  stride 64
    char* H2  = lds + 12288;    // 16 KB, stride 128
    char* H3  = lds + 28672;    // 32 KB, stride 256 (scan scratch before first use)
    const int tid = threadIdx.x;
    const int wv = tid >> 6, lane = tid & 63;
    const int r16 = lane & 15, kg = lane >> 4;

    for (int i = tid; i < 1024; i += 512) reinterpret_cast<unsigned*>(Rin)[i] = 0u;

    // resident weights (loaded once per block)
    const int ft1 = wv & 3;
    bf16x8 a1 = *reinterpret_cast<const bf16x8*>(WT1 + (ft1*16 + r16)*32 + kg*8);
    f32x4 c1v = *reinterpret_cast<const f32x4*>(c1 + ft1*16 + kg*4);
    bf16x8 a2[2];
    #pragma unroll
    for (int ks = 0; ks < 2; ++ks)
        a2[ks] = *reinterpret_cast<const bf16x8*>(WT2 + (wv*16 + r16)*64 + ks*32 + kg*8);
    f32x4 c2v = *reinterpret_cast<const f32x4*>(c2 + wv*16 + kg*4);
    bf16x8 a3[2][4]; f32x4 c3v[2];
    #pragma unroll
    for (int u = 0; u < 2; ++u) {
        int ft = wv*2 + u;
        #pragma unroll
        for (int ks = 0; ks < 4; ++ks)
            a3[u][ks] = *reinterpret_cast<const bf16x8*>(WT3 + (ft*16 + r16)*128 + ks*32 + kg*8);
        c3v[u] = *reinterpret_cast<const f32x4*>(c3 + ft*16 + kg*4);
    }
    bf16x8 a4[8]; f32x4 c4v;
    if (wv < 4) {
        #pragma unroll
        for (int ks = 0; ks < 8; ++ks)
            a4[ks] = *reinterpret_cast<const bf16x8*>(WT4 + r16*256 + ks*32 + kg*8);
        c4v = *reinterpret_cast<const f32x4*>(c4 + kg*4);
    }

    // ---- prologue: per-block occupancy scan (scratch in H3 region) ----
    unsigned* sS  = reinterpret_cast<unsigned*>(H3);          // 512 u32
    unsigned* wbS = reinterpret_cast<unsigned*>(H3 + 2048);   // 8 u32
    unsigned pc0 = (unsigned)__popcll(occW[tid*4+0]);
    unsigned pc1 = (unsigned)__popcll(occW[tid*4+1]);
    unsigned pc2 = (unsigned)__popcll(occW[tid*4+2]);
    unsigned pc3 = (unsigned)__popcll(occW[tid*4+3]);
    unsigned psum = pc0 + pc1 + pc2 + pc3;
    sS[tid] = psum;
    __syncthreads();   // also orders Rin zero vs staging below
    for (int off = 1; off < 512; off <<= 1) {
        unsigned add = (tid >= off) ? sS[tid-off] : 0u;
        __syncthreads();
        sS[tid] += add;
        __syncthreads();
    }
    unsigned ex = sS[tid] - psum;      // exclusive prefix (per 4-word chunk)
    const unsigned tot = sS[511];
    #pragma unroll
    for (int k = 0; k < 8; ++k) {
        int tl = blockIdx.x + 256*k;
        if (tid == (tl >> 2)) {
            unsigned b = ex; int o = tl & 3;
            if (o > 0) b += pc0;
            if (o > 1) b += pc1;
            if (o > 2) b += pc2;
            wbS[k] = b;
        }
    }
    __syncthreads();
    unsigned wb[8];
    #pragma unroll
    for (int k = 0; k < 8; ++k) wb[k] = wbS[k];
    __syncthreads();   // wbS reads complete before H3 reused in L3

    int tile = blockIdx.x;
    unsigned pf;
    if (tid < 288) pf = pooledB[(size_t)tile*288 + tid];
    #pragma unroll 1
    for (int it = 0; it < 8; ++it) {
        // stage current tile input (packed bf16 -> swizzled LDS); K-pad cols stay zero
        if (tid < 288) {
            int ea = 2*tid, eb = ea + 1;
            int ra = ea / 9, ca = ea - ra*9;
            int rb = eb / 9, cb = eb - rb*9;
            *reinterpret_cast<unsigned short*>(Rin + ra*64 + (((ca>>3) ^ (ra&3))<<4) + (ca&7)*2)
                = (unsigned short)(pf & 0xFFFFu);
            *reinterpret_cast<unsigned short*>(Rin + rb*64 + (((cb>>3) ^ (rb&3))<<4) + (cb&7)*2)
                = (unsigned short)(pf >> 16);
        }
        unsigned long long w = occW[tile];
        unsigned base = wb[it];
        // prefetch next tile's input
        if (it < 7 && tid < 288) pf = pooledB[((size_t)tile + 256)*288 + tid];
        __syncthreads();                         // B1
        // L1: K=32 -> 64
        {
            const int rtb = (wv >> 2) * 2;
            #pragma unroll
            for (int i = 0; i < 2; ++i) {
                int r = (rtb + i)*16 + r16;
                bf16x8 b = *reinterpret_cast<const bf16x8*>(Rin + r*64 + ((kg ^ (r&3))<<4));
                f32x4 acc = MFMA16(a1, b, c1v, 0, 0, 0);
                store4(H1, r, 64, ft1*16 + kg*4, acc);
            }
        }
        __syncthreads();                         // B2
        // L2: K=64 -> 128
        #pragma unroll
        for (int rt = 0; rt < 4; ++rt) {
            int r = rt*16 + r16;
            bf16x8 b0 = *reinterpret_cast<const bf16x8*>(H1 + r*128 + ((kg ^ (r&7))<<4));
            bf16x8 b1 = *reinterpret_cast<const bf16x8*>(H1 + r*128 + (((4+kg) ^ (r&7))<<4));
            f32x4 acc = MFMA16(a2[0], b0, c2v, 0, 0, 0);
            acc = MFMA16(a2[1], b1, acc, 0, 0, 0);
            store4(H2, r, 128, wv*16 + kg*4, acc);
        }
        __syncthreads();                         // B3
        // L3: K=128 -> 256 (b-frags shared across the wave's two feature tiles)
        #pragma unroll
        for (int rt = 0; rt < 4; ++rt) {
            int r = rt*16 + r16;
            bf16x8 b[4];
            #pragma unroll
            for (int ks = 0; ks < 4; ++ks)
                b[ks] = *reinterpret_cast<const bf16x8*>(H2 + r*256 + (((ks*4+kg) ^ (r&7))<<4));
            #pragma unroll
            for (int u = 0; u < 2; ++u) {
                f32x4 acc = c3v[u];
                #pragma unroll
                for (int ks = 0; ks < 4; ++ks)
                    acc = MFMA16(a3[u][ks], b[ks], acc, 0, 0, 0);
                store4(H3, r, 256, (wv*2+u)*16 + kg*4, acc);
            }
        }
        __syncthreads();                         // B4
        // L4 (waves 0-3) + unq (wave 4), both scattered by rank
        if (wv < 4) {
            int r = wv*16 + r16;
            f32x4 acc = c4v;
            #pragma unroll
            for (int ks = 0; ks < 8; ++ks) {
                bf16x8 b = *reinterpret_cast<const bf16x8*>(H3 + r*512 + (((ks*4+kg) ^ (r&7))<<4));
                acc = MFMA16(a4[ks], b, acc, 0, 0, 0);
            }
            unsigned rdense = base + (unsigned)__popcll(w & ((1ull << r) - 1ull));
            unsigned rk = ((w >> r) & 1ull) ? rdense
                        : tot + (unsigned)(tile*64 + r) - rdense;
            float4 o;
            o.x = fmaxf(acc[0], 0.f); o.y = fmaxf(acc[1], 0.f);
            o.z = fmaxf(acc[2], 0.f); o.w = fmaxf(acc[3], 0.f);
            *reinterpret_cast<float4*>(outF + (size_t)rk*16 + kg*4) = o;
        } else if (wv == 4) {
            int r = lane, k = tile*64 + r;
            unsigned rdense = base + (unsigned)__popcll(w & ((1ull << r) - 1ull));
            if ((w >> r) & 1ull) {
                reinterpret_cast<float4*>(unqOut)[rdense] =
                    make_float4((float)(k >> 15), (float)((k >> 10) & 31),
                                (float)((k >> 5) & 31), (float)(k & 31));
            } else {
                unsigned er = tot + (unsigned)k - rdense;
                reinterpret_cast<float4*>(unqOut)[er] = make_float4(-1.f,-1.f,-1.f,-1.f);
            }
        }
        tile += 256;
    }
}

extern "C" void kernel_launch(void* const* d_in, const int* in_sizes, int n_in,
                              void* d_out, int out_size, void* d_ws, size_t ws_size,
                              hipStream_t stream) {
    const float* pt_fea = (const float*)d_in[0];
    const int*   xy_ind = (const int*)  d_in[1];
    const float* g0 = (const float*)d_in[2],  *be0 = (const float*)d_in[3];
    const float* m0 = (const float*)d_in[4],  *v0  = (const float*)d_in[5];
    const float* g1 = (const float*)d_in[6],  *be1 = (const float*)d_in[7];
    const float* m1 = (const float*)d_in[8],  *v1  = (const float*)d_in[9];
    const float* g2 = (const float*)d_in[10], *be2 = (const float*)d_in[11];
    const float* m2 = (const float*)d_in[12], *v2  = (const float*)d_in[13];
    const float* g3 = (const float*)d_in[14], *be3 = (const float*)d_in[15];
    const float* m3 = (const float*)d_in[16], *v3  = (const float*)d_in[17];
    const float* w1 = (const float*)d_in[18], *b1  = (const float*)d_in[19];
    const float* w2 = (const float*)d_in[20], *b2  = (const float*)d_in[21];
    const float* w3 = (const float*)d_in[22], *b3  = (const float*)d_in[23];
    const float* w4 = (const float*)d_in[24], *b4  = (const float*)d_in[25];
    const float* wc = (const float*)d_in[26], *bc  = (const float*)d_in[27];

    float* dout = (float*)d_out;

    // workspace layout (u32 units)
    unsigned* ws0 = (unsigned*)d_ws;
    unsigned long long* occW = (unsigned long long*)ws0;     // 2048 u64 = [0,4096)
    unsigned* bucketFill = ws0 + 4096;                       // 512
    unsigned* pooledB    = ws0 + 4608;                       // 512*1152 packed bf16 pairs
    unsigned* bP         = pooledB + 512*1152;               // 5 planes x 512*BCAP
    unsigned* wtBase     = bP + 5*(size_t)PLANE;
    unsigned short* WT1  = (unsigned short*)wtBase;          // 64*32
    unsigned short* WT2  = WT1 + 2048;                       // 128*64
    unsigned short* WT3  = WT2 + 8192;                       // 256*128
    unsigned short* WT4  = WT3 + 32768;                      // 16*256
    float* c1 = (float*)(WT4 + 4096);
    float* c2 = c1 + 64;
    float* c3 = c2 + 128;
    float* c4 = c3 + 256;

    k_fold<<<188, 256, 0, stream>>>(g0,be0,m0,v0, g1,be1,m1,v1, g2,be2,m2,v2, g3,be3,m3,v3,
                                    w1,b1, w2,b2, w3,b3, w4,b4, wc,bc,
                                    WT1,c1, WT2,c2, WT3,c3, WT4,c4, bucketFill);
    kC<<<500, 512, 0, stream>>>(xy_ind, pt_fea, bucketFill, bP);
    kD<<<512, 1024, 0, stream>>>(bucketFill, bP, pooledB, occW);
    k_mlp<<<256, 512, 0, stream>>>(pooledB, occW,
                                   WT1,c1, WT2,c2, WT3,c3, WT4,c4, dout, dout + OUT_OFF);
}